// Round 4
// baseline (4871.125 us; speedup 1.0000x reference)
//
#include <hip/hip_runtime.h>
#include <hip/hip_cooperative_groups.h>
#include <stdint.h>

namespace cg = cooperative_groups;

#define ALPHA 0.1f
#define NN 20000
#define DF 768
#define NE 200000
#define NB 64
#define TSEQ 128
#define SF 128
#define HS 512
#define NCLS 14

typedef __attribute__((ext_vector_type(8))) short short8;
typedef __attribute__((ext_vector_type(4))) float f32x4;
typedef __attribute__((ext_vector_type(4))) unsigned int u32x4;

// ---------------- workspace layout (bytes) ----------------
#define OFF_DEG     0u           // int[20000]
#define OFF_CSRC    80000u       // int[20000]
#define OFF_CNTB    160000u      // int[64]
#define OFF_FLAG64  176640u      // int[1] : 1 if indices are int64
#define ZERO_INTS   44161u       // zero [0, 176644)
#define OFF_ROWPTR  176896u      // int[20001]
#define OFF_CURSOR  257024u      // int[20000]
#define OFF_DINV    337024u      // float[20000]
#define OFF_COL     417024u      // int[200000]
#define OFF_WGT     1217024u     // float[200000]
#define OFF_V0      2017280u     // float[20000*64]
#define OFF_V1      7137280u     // float[20000*64]
#define OFF_HBUF    12257280u    // u32 [2][2][8][32][128] tagged words (512 KB)
#define OFF_YSEQ    12781568u    // float[64*1024]
#define OFF_SH1     13043712u    // float[64*512]
#define OFF_SH2     13174784u    // float[64*256]
#define OFF_PART    13240320u    // float[16][64][768]
#define OFF_POOL    16386048u    // float[64*768]
#define OFF_GH1     16582656u    // float[64*384]
#define OFF_GH2     16680960u    // float[64*192]

__device__ __forceinline__ unsigned short f2b(float f) {
  union { float f; unsigned u; } v; v.f = f;
  unsigned u = v.u;
  return (unsigned short)((u + 0x7FFFu + ((u >> 16) & 1u)) >> 16);
}

__device__ __forceinline__ int idx_at(const int* p, long long i, int mode64) {
  return mode64 ? p[2*i] : p[i];   // little-endian low word
}

// ---------------- small utility kernels ----------------
__global__ void zero_ints_kernel(int* p, int n) {
  int i = blockIdx.x * blockDim.x + threadIdx.x;
  if (i < n) p[i] = 0;
}

// 64-lane parallel i64 detection (was single-thread: ~256 serial loads)
__global__ void detect_i64_kernel(const int* e, int* flag) {
  int lane = threadIdx.x;
  int ok = 1;
  for (int i = lane; i < 256; i += 64) ok &= (e[2 * i + 1] == 0);
  ok = __all(ok);
  if (lane == 0 && blockIdx.x == 0) *flag = ok ? 1 : 0;
}

__global__ void hist_kernel(const int* e, const int* batch, int* deg, int* csrc,
                            int* cntb, const int* flag) {
  int i = blockIdx.x * blockDim.x + threadIdx.x;
  int m = *flag;
  if (i < NE) {
    int s = idx_at(e, i, m);
    int d = idx_at(e, (long long)NE + i, m);
    atomicAdd(&csrc[s], 1);
    atomicAdd(&deg[d], 1);
  }
  if (i < NN) atomicAdd(&cntb[idx_at(batch, i, m)], 1);
}

__global__ void dinv_kernel(const int* deg, float* dinv) {
  int i = blockIdx.x * blockDim.x + threadIdx.x;
  if (i < NN) dinv[i] = rsqrtf((float)(deg[i] + 1));   // +1 self loop, >=1
}

__global__ void scan_kernel(const int* cnt, int* row_ptr, int* cursor) {
  __shared__ int sA[1024], sB[1024];
  int tid = threadIdx.x;
  int carry = 0;
  const int nch = (NN + 1023) / 1024;
  for (int c = 0; c < nch; ++c) {
    int i = c * 1024 + tid;
    int v = (i < NN) ? cnt[i] : 0;
    sA[tid] = v;
    __syncthreads();
    int* src = sA; int* dst = sB;
    for (int off = 1; off < 1024; off <<= 1) {
      dst[tid] = src[tid] + (tid >= off ? src[tid - off] : 0);
      __syncthreads();
      int* t = src; src = dst; dst = t;
    }
    if (i < NN) { int ex = carry + src[tid] - v; row_ptr[i] = ex; cursor[i] = ex; }
    carry += src[1023];
    __syncthreads();
  }
  if (tid == 0) row_ptr[NN] = carry;
}

__global__ void fill_kernel(const int* e, const float* dinv, int* cursor,
                            int* colA, float* wgt, const int* flag) {
  int i = blockIdx.x * blockDim.x + threadIdx.x;
  if (i >= NE) return;
  int m = *flag;
  int s = idx_at(e, i, m);
  int d = idx_at(e, (long long)NE + i, m);
  int pos = atomicAdd(&cursor[s], 1);
  colA[pos] = d;
  wgt[pos] = dinv[s] * dinv[d];
}

__global__ void v0init_kernel(const int* batch, float* v0, const int* flag) {
  int i = blockIdx.x * blockDim.x + threadIdx.x;
  if (i >= NN * 64) return;
  int n = i >> 6, b = i & 63;
  v0[i] = (idx_at(batch, n, *flag) == b) ? 1.0f : 0.0f;
}

// ---------------- fused 16-hop APPNP (cooperative, grid-sync between hops) --
// 1024 blocks x 256 thr = 4096 waves, 4 blocks/CU guaranteed co-resident
// (launch_bounds(256,4) caps VGPR<=128, LDS=0). One wave per node per
// grid-stride round; lane = graph id. Replaces 16 serial dispatches:
// removes 15 launch/drain gaps; V0/V1 stay MALL-resident throughout.
__global__ __launch_bounds__(256, 4) void hop16_kernel(
    float* __restrict__ V0, float* __restrict__ V1,
    const int* __restrict__ row_ptr, const int* __restrict__ colA,
    const float* __restrict__ wgt, const float* __restrict__ dinv,
    const int* __restrict__ batch, const int* __restrict__ flag) {
  cg::grid_group grid = cg::this_grid();
  const int lane = threadIdx.x & 63;
  const int wid0 = (blockIdx.x * blockDim.x + threadIdx.x) >> 6;  // 0..4095
  const int m64 = *flag;
  for (int h = 0; h < 16; ++h) {
    const float* __restrict__ vin  = (h & 1) ? V1 : V0;
    float* __restrict__       vout = (h & 1) ? V0 : V1;
    for (int wid = wid0; wid < NN; wid += 4096) {
      float di = dinv[wid];
      float acc = di * di * vin[wid * 64 + lane];
      int e0 = __builtin_amdgcn_readfirstlane(row_ptr[wid]);
      int e1 = __builtin_amdgcn_readfirstlane(row_ptr[wid + 1]);
      int e = e0;
      for (; e + 8 <= e1; e += 8) {
        int c0 = colA[e],     c1 = colA[e + 1], c2 = colA[e + 2], c3 = colA[e + 3];
        int c4 = colA[e + 4], c5 = colA[e + 5], c6 = colA[e + 6], c7 = colA[e + 7];
        float w0 = wgt[e],     w1 = wgt[e + 1], w2 = wgt[e + 2], w3 = wgt[e + 3];
        float w4 = wgt[e + 4], w5 = wgt[e + 5], w6 = wgt[e + 6], w7 = wgt[e + 7];
        float v0 = vin[(size_t)c0 * 64 + lane];
        float v1 = vin[(size_t)c1 * 64 + lane];
        float v2 = vin[(size_t)c2 * 64 + lane];
        float v3 = vin[(size_t)c3 * 64 + lane];
        float v4 = vin[(size_t)c4 * 64 + lane];
        float v5 = vin[(size_t)c5 * 64 + lane];
        float v6 = vin[(size_t)c6 * 64 + lane];
        float v7 = vin[(size_t)c7 * 64 + lane];
        acc += w0 * v0 + w1 * v1 + w2 * v2 + w3 * v3;
        acc += w4 * v4 + w5 * v5 + w6 * v6 + w7 * v7;
      }
      for (; e + 4 <= e1; e += 4) {
        int c0 = colA[e], c1 = colA[e + 1], c2 = colA[e + 2], c3 = colA[e + 3];
        float w0 = wgt[e], w1 = wgt[e + 1], w2 = wgt[e + 2], w3 = wgt[e + 3];
        float v0 = vin[(size_t)c0 * 64 + lane];
        float v1 = vin[(size_t)c1 * 64 + lane];
        float v2 = vin[(size_t)c2 * 64 + lane];
        float v3 = vin[(size_t)c3 * 64 + lane];
        acc += w0 * v0 + w1 * v1 + w2 * v2 + w3 * v3;
      }
      for (; e < e1; ++e) acc += wgt[e] * vin[(size_t)colA[e] * 64 + lane];
      float y0 = (idx_at(batch, wid, m64) == lane) ? ALPHA : 0.0f;
      vout[wid * 64 + lane] = (1.0f - ALPHA) * acc + y0;
    }
    if (h < 15) {
      __threadfence();     // device-scope release of vout writes
      grid.sync();         // all blocks advance to next hop together
    }
  }
}

// pooled_unnorm partials: 48 f-tiles x 16 node-chunks, lane = graph id
__global__ void spmm_kernel(const float* __restrict__ S, const float* __restrict__ x,
                            float* __restrict__ partial) {
  int wid = (blockIdx.x * blockDim.x + threadIdx.x) >> 6;   // 768 waves
  int lane = threadIdx.x & 63;
  int ft = wid % 48, ch = wid / 48;
  if (ch >= 16) return;
  int f0 = ft * 16;
  int n0 = ch * 1250, n1 = n0 + 1250;
  float acc[16];
#pragma unroll
  for (int f = 0; f < 16; ++f) acc[f] = 0.0f;
  for (int n = n0; n < n1; ++n) {
    float sv = S[n * 64 + lane];
    const float* xr = x + (size_t)n * DF + f0;
#pragma unroll
    for (int f = 0; f < 16; ++f) acc[f] += sv * xr[f];
  }
  float* pr = partial + ((size_t)(ch * 64 + lane)) * DF + f0;
#pragma unroll
  for (int f = 0; f < 16; ++f) pr[f] = acc[f];
}

__global__ void reduce_pool_kernel(const float* __restrict__ partial, const int* __restrict__ cntb,
                                   float* __restrict__ pooled) {
  int i = blockIdx.x * blockDim.x + threadIdx.x;
  if (i >= 64 * DF) return;
  int b = i / DF, f = i - b * DF;
  float s = 0.0f;
  for (int c = 0; c < 16; ++c) s += partial[((size_t)(c * 64 + b)) * DF + f];
  int cnt = cntb[b]; if (cnt < 1) cnt = 1;
  pooled[i] = s / (float)cnt;
}

// C[M,N] = act(A[M,K] @ W[N,K]^T + bias), optionally accumulate into C
__global__ void mlp_layer_kernel(const float* __restrict__ A, const float* __restrict__ W,
                                 const float* __restrict__ bias, float* __restrict__ C,
                                 int M, int N, int K, int relu, int accum) {
  int i = blockIdx.x * blockDim.x + threadIdx.x;
  if (i >= M * N) return;
  int mrow = i / N, n = i - mrow * N;
  float acc = bias[n];
  const float4* a4 = (const float4*)(A + (size_t)mrow * K);
  const float4* w4 = (const float4*)(W + (size_t)n * K);
  int k4 = K >> 2;
#pragma unroll 4
  for (int k = 0; k < k4; ++k) {
    float4 av = a4[k], wv = w4[k];
    acc += av.x * wv.x + av.y * wv.y + av.z * wv.z + av.w * wv.w;
  }
  if (relu) acc = fmaxf(acc, 0.0f);
  if (accum) C[i] += acc; else C[i] = acc;
}

// ---------------- GRU recurrent kernel (1 wave/block, tagged-word exchange) -
// 512 blocks x 64 threads: blockIdx = d*256 + g*32 + rk. Weights in VGPRs
// (R3 structure). Exchange reverted to R1's tag-per-word direct polling —
// measured 2x lower per-exchange latency than the flag protocol (R1: 2.05
// us/exchange vs R3: 4.0): chain is store(one-way) + poll(detect==data,
// ~1 RT) instead of store-ack RT + flag RT + gather RT.
//   hbuf[slot][d][g][rk][128]: word = (tag<<16)|bf16, rank slab contiguous
//   (512 B). Producer: 4 dword stores (lanes<32), NO vmcnt, NO flag.
//   Consumer: 16 dwordx4 chunks/lane with got-bitmask; matched chunks are
//   scattered to LDS immediately and never re-read. hbuf zeroed per launch
//   (first-launch garbage could alias tag 1; cross-replay tags can't).
// Slot reuse 2-deep safe: rank producing t+1 gathered all of t, so every
// rank produced t, so every rank finished gathering t-1 (needed it for t).
__global__ __launch_bounds__(64, 1) void gru_kernel(
    const float* __restrict__ seq,
    const float* __restrict__ wih_f, const float* __restrict__ whh_f,
    const float* __restrict__ bih_f, const float* __restrict__ bhh_f,
    const float* __restrict__ wih_b, const float* __restrict__ whh_b,
    const float* __restrict__ bih_b, const float* __restrict__ bhh_b,
    unsigned* __restrict__ hbuf, float* __restrict__ y_seq) {
  __shared__ unsigned short hl[8 * 648];   // [8 seqs][h(512) | x(128) | pad]

  const int lane = threadIdx.x;           // 0..63
  const int quad = lane >> 4, l15 = lane & 15;
  const int d  = blockIdx.x >> 8;         // 0 fwd, 1 bwd
  const int g  = (blockIdx.x >> 5) & 7;   // 8 groups
  const int rk = blockIdx.x & 31;         // 32 ranks
  const int seqbase = g * 8;
  const int c0 = rk * 16;

  const float* WHHd = d ? whh_b : whh_f;
  const float* WIHd = d ? wih_b : wih_f;
  const float* BIHd = d ? bih_b : bih_f;
  const float* BHHd = d ? bhh_b : bhh_f;

  // ---- weight fragments -> registers (once) ----
  auto ldw = [&](int gcol, int j) -> short8 {
    int k0 = j * 32 + quad * 8;
    const float* p = (k0 < 512) ? (WHHd + (size_t)gcol * 512 + k0)
                                : (WIHd + (size_t)gcol * 128 + (k0 - 512));
    float4 f0 = *(const float4*)p;
    float4 f1 = *(const float4*)(p + 4);
    short8 r;
    r[0] = (short)f2b(f0.x); r[1] = (short)f2b(f0.y);
    r[2] = (short)f2b(f0.z); r[3] = (short)f2b(f0.w);
    r[4] = (short)f2b(f1.x); r[5] = (short)f2b(f1.y);
    r[6] = (short)f2b(f1.z); r[7] = (short)f2b(f1.w);
    return r;
  };
  short8 wr[20], wz[20], wn[20];
#pragma unroll
  for (int j = 0; j < 20; ++j) {
    wr[j] = ldw(c0 + l15, j);
    wz[j] = ldw(512 + c0 + l15, j);
    wn[j] = ldw(1024 + c0 + l15, j);
  }

  // ---- x staging: 1 lane does (seq = lane>>3, 16 k-chunk) ----
  auto stage_x = [&](int t_x) {
    int tt = d ? (127 - t_x) : t_x;
    int s = lane >> 3, k0 = (lane & 7) * 16;
    const float* sp = seq + (size_t)(seqbase + s) * (TSEQ * SF) + tt * SF + k0;
    float4 a = *(const float4*)sp;
    float4 b = *(const float4*)(sp + 4);
    float4 c = *(const float4*)(sp + 8);
    float4 e = *(const float4*)(sp + 12);
    unsigned* xq = (unsigned*)(hl + s * 648 + 512 + k0);   // 16B aligned
    xq[0] = (unsigned)f2b(a.x) | ((unsigned)f2b(a.y) << 16);
    xq[1] = (unsigned)f2b(a.z) | ((unsigned)f2b(a.w) << 16);
    xq[2] = (unsigned)f2b(b.x) | ((unsigned)f2b(b.y) << 16);
    xq[3] = (unsigned)f2b(b.z) | ((unsigned)f2b(b.w) << 16);
    xq[4] = (unsigned)f2b(c.x) | ((unsigned)f2b(c.y) << 16);
    xq[5] = (unsigned)f2b(c.z) | ((unsigned)f2b(c.w) << 16);
    xq[6] = (unsigned)f2b(e.x) | ((unsigned)f2b(e.y) << 16);
    xq[7] = (unsigned)f2b(e.z) | ((unsigned)f2b(e.w) << 16);
  };

  // ---- init: h(0)=0, stage x(0) ----
  for (int i = lane; i < 8 * 512; i += 64)
    hl[(i >> 9) * 648 + (i & 511)] = 0;
  stage_x(0);

  const float b_r  = BIHd[c0 + l15] + BHHd[c0 + l15];
  const float b_z  = BIHd[512 + c0 + l15] + BHHd[512 + c0 + l15];
  const float b_in = BIHd[1024 + c0 + l15];
  const float b_hn = BHHd[1024 + c0 + l15];

  float hprev[4] = {0, 0, 0, 0};
  float msum[4]  = {0, 0, 0, 0};
  float mxv[4]   = {-1e30f, -1e30f, -1e30f, -1e30f};

  for (int t = 0; t < 128; ++t) {
    // ---- GEMM: 60 MFMAs, A-frag read once per kc, shared by r/z/n ----
    f32x4 ar = {0, 0, 0, 0}, az = {0, 0, 0, 0};
    f32x4 anh = {0, 0, 0, 0}, anx = {0, 0, 0, 0};
    const unsigned short* arow = hl + (l15 & 7) * 648 + quad * 8;
#pragma unroll
    for (int kc = 0; kc < 20; ++kc) {
      short8 af = *(const short8*)(arow + kc * 32);
      ar = __builtin_amdgcn_mfma_f32_16x16x32_bf16(af, wr[kc], ar, 0, 0, 0);
      az = __builtin_amdgcn_mfma_f32_16x16x32_bf16(af, wz[kc], az, 0, 0, 0);
      if (kc < 16)
        anh = __builtin_amdgcn_mfma_f32_16x16x32_bf16(af, wn[kc], anh, 0, 0, 0);
      else
        anx = __builtin_amdgcn_mfma_f32_16x16x32_bf16(af, wn[kc], anx, 0, 0, 0);
    }

    // ---- gates: fully in-register (lane: col=l15, rows=quad*4+rr) ----
    float h2v[4];
#pragma unroll
    for (int rr = 0; rr < 4; ++rr) {
      float r = 1.0f / (1.0f + __expf(-(ar[rr] + b_r)));
      float z = 1.0f / (1.0f + __expf(-(az[rr] + b_z)));
      float narg = anx[rr] + b_in + r * (anh[rr] + b_hn);
      float e2 = __expf(-2.0f * fabsf(narg));
      float nt = (1.0f - e2) / (1.0f + e2);
      nt = (narg < 0.0f) ? -nt : nt;
      float h2 = (1.0f - z) * nt + z * hprev[rr];
      hprev[rr] = h2; msum[rr] += h2; mxv[rr] = fmaxf(mxv[rr], h2);
      h2v[rr] = h2;
    }

    if (t < 127) {
      const int slot = (t + 1) & 1;
      const unsigned tag = (unsigned)(t + 1);
      unsigned* sb = hbuf + (((size_t)(slot * 2 + d) * 8 + g) * 32 + rk) * 128;
      // ---- producer: 4 tagged dword stores (rows 0-7 live in lanes 0-31) --
#pragma unroll
      for (int rr = 0; rr < 4; ++rr) {
        if (lane < 32) {
          unsigned word = (tag << 16) | (unsigned)f2b(h2v[rr]);
          unsigned* dp = sb + (quad * 4 + rr) * 16 + l15;
          asm volatile("global_store_dword %0, %1, off sc0 sc1"
                       :: "v"(dp), "v"(word) : "memory");
        }
      }
      // ---- stage x(t+1): overlaps store flight + others' production ----
      stage_x(t + 1);
      // ---- consumer: poll 16 dwordx4 chunks with got-bitmask ----
      const unsigned* db = hbuf + (((size_t)(slot * 2 + d) * 8 + g) * 32) * 128;
      unsigned got = 0;
      int guard = 0;
      u32x4 v0, v1, v2, v3, v4, v5, v6, v7, v8, v9, va, vb, vc, vd, ve, vf;
#define ISSUE(J, VV)                                                          \
      if (!(got & (1u << J)))                                                 \
        asm volatile("global_load_dwordx4 %0, %1, off sc0 sc1"                \
                     : "=v"(VV) : "v"(db + J * 256 + lane * 4) : "memory");
#define CHECK(J, VV)                                                          \
      if (!(got & (1u << J))) {                                               \
        if ((VV[0] >> 16) == tag && (VV[1] >> 16) == tag &&                   \
            (VV[2] >> 16) == tag && (VV[3] >> 16) == tag) {                   \
          int rk2 = 2 * J + (lane >> 5);                                      \
          int s = (lane & 31) >> 2, c4 = (lane & 3) * 4;                      \
          unsigned* dp = (unsigned*)(hl + s * 648 + rk2 * 16 + c4);           \
          dp[0] = (VV[0] & 0xFFFFu) | (VV[1] << 16);                          \
          dp[1] = (VV[2] & 0xFFFFu) | (VV[3] << 16);                          \
          got |= 1u << J;                                                     \
        }                                                                     \
      }
      for (;;) {
        ISSUE(0, v0)  ISSUE(1, v1)  ISSUE(2, v2)  ISSUE(3, v3)
        ISSUE(4, v4)  ISSUE(5, v5)  ISSUE(6, v6)  ISSUE(7, v7)
        ISSUE(8, v8)  ISSUE(9, v9)  ISSUE(10, va) ISSUE(11, vb)
        ISSUE(12, vc) ISSUE(13, vd) ISSUE(14, ve) ISSUE(15, vf)
        asm volatile("s_waitcnt vmcnt(0)" ::: "memory");
        __builtin_amdgcn_sched_barrier(0);
        CHECK(0, v0)  CHECK(1, v1)  CHECK(2, v2)  CHECK(3, v3)
        CHECK(4, v4)  CHECK(5, v5)  CHECK(6, v6)  CHECK(7, v7)
        CHECK(8, v8)  CHECK(9, v9)  CHECK(10, va) CHECK(11, vb)
        CHECK(12, vc) CHECK(13, vd) CHECK(14, ve) CHECK(15, vf)
        if (got == 0xFFFFu) break;
        if (++guard > (1 << 20)) break;
        __builtin_amdgcn_s_sleep(1);
      }
#undef ISSUE
#undef CHECK
    }
  }

  // ---- epilogue: seq1 + seq2 = mean + max over T ----
  if (lane < 32) {
#pragma unroll
    for (int rr = 0; rr < 4; ++rr) {
      int row = (lane >> 4) * 4 + rr;
      y_seq[(size_t)(seqbase + row) * 1024 + d * 512 + c0 + l15] =
          msum[rr] * (1.0f / 128.0f) + mxv[rr];
    }
  }
}

// ---------------- launcher ----------------
extern "C" void kernel_launch(void* const* d_in, const int* in_sizes, int n_in,
                              void* d_out, int out_size, void* d_ws, size_t ws_size,
                              hipStream_t stream) {
  const float* x      = (const float*)d_in[0];
  const int*   eidx   = (const int*)d_in[1];
  const float* seq    = (const float*)d_in[2];
  const int*   batch  = (const int*)d_in[3];
  const float* wih_f  = (const float*)d_in[4];
  const float* whh_f  = (const float*)d_in[5];
  const float* bih_f  = (const float*)d_in[6];
  const float* bhh_f  = (const float*)d_in[7];
  const float* wih_b  = (const float*)d_in[8];
  const float* whh_b  = (const float*)d_in[9];
  const float* bih_b  = (const float*)d_in[10];
  const float* bhh_b  = (const float*)d_in[11];
  const float* mg_w0  = (const float*)d_in[12];
  const float* mg_b0  = (const float*)d_in[13];
  const float* mg_w1  = (const float*)d_in[14];
  const float* mg_b1  = (const float*)d_in[15];
  const float* mg_w2  = (const float*)d_in[16];
  const float* mg_b2  = (const float*)d_in[17];
  const float* ms_w0  = (const float*)d_in[18];
  const float* ms_b0  = (const float*)d_in[19];
  const float* ms_w1  = (const float*)d_in[20];
  const float* ms_b1  = (const float*)d_in[21];
  const float* ms_w2  = (const float*)d_in[22];
  const float* ms_b2  = (const float*)d_in[23];
  float* out = (float*)d_out;
  char* ws = (char*)d_ws;

  int*   deg     = (int*)(ws + OFF_DEG);
  int*   csrc    = (int*)(ws + OFF_CSRC);
  int*   cntb    = (int*)(ws + OFF_CNTB);
  int*   flag    = (int*)(ws + OFF_FLAG64);
  int*   row_ptr = (int*)(ws + OFF_ROWPTR);
  int*   cursor  = (int*)(ws + OFF_CURSOR);
  float* dinv    = (float*)(ws + OFF_DINV);
  int*   colA    = (int*)(ws + OFF_COL);
  float* wgtA    = (float*)(ws + OFF_WGT);
  float* V0      = (float*)(ws + OFF_V0);
  float* V1      = (float*)(ws + OFF_V1);
  unsigned* hbuf = (unsigned*)(ws + OFF_HBUF);
  float* y_seq   = (float*)(ws + OFF_YSEQ);
  float* sh1     = (float*)(ws + OFF_SH1);
  float* sh2     = (float*)(ws + OFF_SH2);
  float* part    = (float*)(ws + OFF_PART);
  float* pooled  = (float*)(ws + OFF_POOL);
  float* gh1     = (float*)(ws + OFF_GH1);
  float* gh2     = (float*)(ws + OFF_GH2);

  // ---- graph prep (CSR for A^T, degrees, batch counts) ----
  zero_ints_kernel<<<(ZERO_INTS + 255) / 256, 256, 0, stream>>>((int*)ws, (int)ZERO_INTS);
  zero_ints_kernel<<<512, 256, 0, stream>>>((int*)(ws + OFF_HBUF), 131072);  // tag slabs
  detect_i64_kernel<<<1, 64, 0, stream>>>(eidx, flag);
  hist_kernel<<<(NE + 255) / 256, 256, 0, stream>>>(eidx, batch, deg, csrc, cntb, flag);
  dinv_kernel<<<(NN + 255) / 256, 256, 0, stream>>>(deg, dinv);
  scan_kernel<<<1, 1024, 0, stream>>>(csrc, row_ptr, cursor);
  fill_kernel<<<(NE + 255) / 256, 256, 0, stream>>>(eidx, dinv, cursor, colA, wgtA, flag);
  v0init_kernel<<<(NN * 64 + 255) / 256, 256, 0, stream>>>(batch, V0, flag);

  // ---- APPNP: all 16 hops in ONE cooperative kernel ----
  {
    float* v0p = V0; float* v1p = V1;
    const int* rp = row_ptr; const int* ca = colA; const float* wg = wgtA;
    const float* dv = dinv; const int* bp = batch; const int* fl = flag;
    void* hargs[] = {&v0p, &v1p, (void*)&rp, (void*)&ca, (void*)&wg,
                     (void*)&dv, (void*)&bp, (void*)&fl};
    hipLaunchCooperativeKernel((void*)hop16_kernel, dim3(1024), dim3(256),
                               hargs, 0, stream);
  }

  // ---- BiGRU (fused gi + recurrent + pooling), 1 wave/block ----
  gru_kernel<<<512, 64, 0, stream>>>(
      seq, wih_f, whh_f, bih_f, bhh_f, wih_b, whh_b, bih_b, bhh_b, hbuf, y_seq);

  // ---- seq MLP: 1024 -> 512 -> 256 -> 14 (writes d_out) ----
  mlp_layer_kernel<<<(64 * 512 + 255) / 256, 256, 0, stream>>>(y_seq, ms_w0, ms_b0, sh1,
                                                               64, 512, 1024, 1, 0);
  mlp_layer_kernel<<<(64 * 256 + 255) / 256, 256, 0, stream>>>(sh1, ms_w1, ms_b1, sh2,
                                                               64, 256, 512, 1, 0);
  mlp_layer_kernel<<<(64 * NCLS + 255) / 256, 256, 0, stream>>>(sh2, ms_w2, ms_b2, out,
                                                                64, NCLS, 256, 0, 0);

  // ---- pooled = (S^T x) / cnt ; after 16 hops result is in V0 ----
  spmm_kernel<<<(768 * 64) / 256, 256, 0, stream>>>(V0, x, part);
  reduce_pool_kernel<<<(64 * DF + 255) / 256, 256, 0, stream>>>(part, cntb, pooled);

  // ---- graph MLP: 768 -> 384 -> 192 -> 14 (accumulates into d_out) ----
  mlp_layer_kernel<<<(64 * 384 + 255) / 256, 256, 0, stream>>>(pooled, mg_w0, mg_b0, gh1,
                                                               64, 384, 768, 1, 0);
  mlp_layer_kernel<<<(64 * 192 + 255) / 256, 256, 0, stream>>>(gh1, mg_w1, mg_b1, gh2,
                                                               64, 192, 384, 1, 0);
  mlp_layer_kernel<<<(64 * NCLS + 255) / 256, 256, 0, stream>>>(gh2, mg_w2, mg_b2, out,
                                                                64, NCLS, 192, 0, 1);
  (void)in_sizes; (void)n_in; (void)out_size; (void)ws_size;
}

// Round 5
// 1528.687 us; speedup vs baseline: 3.1865x; 3.1865x over previous
//
#include <hip/hip_runtime.h>
#include <stdint.h>

#define ALPHA 0.1f
#define NN 20000
#define DF 768
#define NE 200000
#define NB 64
#define TSEQ 128
#define SF 128
#define HS 512
#define NCLS 14

typedef __attribute__((ext_vector_type(8))) short short8;
typedef __attribute__((ext_vector_type(4))) float f32x4;
typedef __attribute__((ext_vector_type(4))) unsigned int u32x4;

// ---------------- workspace layout (bytes) ----------------
#define OFF_DEG     0u           // int[20000]
#define OFF_CSRC    80000u       // int[20000]
#define OFF_CNTB    160000u      // int[64]
#define OFF_FLAG64  176640u      // int[1] : 1 if indices are int64
#define ZERO_INTS   44161u       // zero [0, 176644)
#define OFF_ROWPTR  176896u      // int[20001]
#define OFF_CURSOR  257024u      // int[20000]
#define OFF_DINV    337024u      // float[20000]
#define OFF_COL     417024u      // int[200000]
#define OFF_WGT     1217024u     // float[200000]
#define OFF_V0      2017280u     // float[20000*64]
#define OFF_V1      7137280u     // float[20000*64]
#define OFF_HBUF    12257280u    // u32 [2][2][64][256]  (2 x bf16 h, untagged)
#define OFF_HFLAG   12519424u    // u32 [2][2][8][64]    (rank flags = step tag)
#define OFF_YSEQ    12781568u    // float[64*1024]
#define OFF_SH1     13043712u    // float[64*512]
#define OFF_SH2     13174784u    // float[64*256]
#define OFF_PART    13240320u    // float[16][64][768]
#define OFF_POOL    16386048u    // float[64*768]
#define OFF_GH1     16582656u    // float[64*384]
#define OFF_GH2     16680960u    // float[64*192]

__device__ __forceinline__ unsigned short f2b(float f) {
  union { float f; unsigned u; } v; v.f = f;
  unsigned u = v.u;
  return (unsigned short)((u + 0x7FFFu + ((u >> 16) & 1u)) >> 16);
}

__device__ __forceinline__ int idx_at(const int* p, long long i, int mode64) {
  return mode64 ? p[2*i] : p[i];   // little-endian low word
}

// ---------------- small utility kernels ----------------
__global__ void zero_ints_kernel(int* p, int n) {
  int i = blockIdx.x * blockDim.x + threadIdx.x;
  if (i < n) p[i] = 0;
}

// 64-lane parallel i64 detection
__global__ void detect_i64_kernel(const int* e, int* flag) {
  int lane = threadIdx.x;
  int ok = 1;
  for (int i = lane; i < 256; i += 64) ok &= (e[2 * i + 1] == 0);
  ok = __all(ok);
  if (lane == 0 && blockIdx.x == 0) *flag = ok ? 1 : 0;
}

__global__ void hist_kernel(const int* e, const int* batch, int* deg, int* csrc,
                            int* cntb, const int* flag) {
  int i = blockIdx.x * blockDim.x + threadIdx.x;
  int m = *flag;
  if (i < NE) {
    int s = idx_at(e, i, m);
    int d = idx_at(e, (long long)NE + i, m);
    atomicAdd(&csrc[s], 1);
    atomicAdd(&deg[d], 1);
  }
  if (i < NN) atomicAdd(&cntb[idx_at(batch, i, m)], 1);
}

__global__ void dinv_kernel(const int* deg, float* dinv) {
  int i = blockIdx.x * blockDim.x + threadIdx.x;
  if (i < NN) dinv[i] = rsqrtf((float)(deg[i] + 1));   // +1 self loop, >=1
}

__global__ void scan_kernel(const int* cnt, int* row_ptr, int* cursor) {
  __shared__ int sA[1024], sB[1024];
  int tid = threadIdx.x;
  int carry = 0;
  const int nch = (NN + 1023) / 1024;
  for (int c = 0; c < nch; ++c) {
    int i = c * 1024 + tid;
    int v = (i < NN) ? cnt[i] : 0;
    sA[tid] = v;
    __syncthreads();
    int* src = sA; int* dst = sB;
    for (int off = 1; off < 1024; off <<= 1) {
      dst[tid] = src[tid] + (tid >= off ? src[tid - off] : 0);
      __syncthreads();
      int* t = src; src = dst; dst = t;
    }
    if (i < NN) { int ex = carry + src[tid] - v; row_ptr[i] = ex; cursor[i] = ex; }
    carry += src[1023];
    __syncthreads();
  }
  if (tid == 0) row_ptr[NN] = carry;
}

__global__ void fill_kernel(const int* e, const float* dinv, int* cursor,
                            int* colA, float* wgt, const int* flag) {
  int i = blockIdx.x * blockDim.x + threadIdx.x;
  if (i >= NE) return;
  int m = *flag;
  int s = idx_at(e, i, m);
  int d = idx_at(e, (long long)NE + i, m);
  int pos = atomicAdd(&cursor[s], 1);
  colA[pos] = d;
  wgt[pos] = dinv[s] * dinv[d];
}

__global__ void v0init_kernel(const int* batch, float* v0, const int* flag) {
  int i = blockIdx.x * blockDim.x + threadIdx.x;
  if (i >= NN * 64) return;
  int n = i >> 6, b = i & 63;
  v0[i] = (idx_at(batch, n, *flag) == b) ? 1.0f : 0.0f;
}

// one wave per node; quad-parallel edges: quad q handles edge e+q, each lane
// gathers float4 of cols l15*4..+3 -> 1 KB (4 edges) per gather instruction,
// 8 edges in flight (unroll 2). Self-loop folded in as pseudo-edge (w=di^2).
// Cross-quad sum via shfl_xor(16,32); quad 0 stores the 256 B row as float4.
__global__ __launch_bounds__(256) void hop_kernel(
    const float* __restrict__ vin, float* __restrict__ vout,
    const int* __restrict__ row_ptr, const int* __restrict__ colA,
    const float* __restrict__ wgt, const float* __restrict__ dinv,
    const int* __restrict__ batch, const int* __restrict__ flag) {
  int wid = (blockIdx.x * blockDim.x + threadIdx.x) >> 6;
  int lane = threadIdx.x & 63;
  if (wid >= NN) return;
  const int quad = lane >> 4, l15 = lane & 15;
  const int c4 = l15 * 4;
  float di = dinv[wid];
  int e0 = __builtin_amdgcn_readfirstlane(row_ptr[wid]);
  int e1 = __builtin_amdgcn_readfirstlane(row_ptr[wid + 1]);

  float ax, ay, az, aw;
  {  // self-loop as first 4-edge batch (quad 0 active)
    float w = (quad == 0) ? di * di : 0.0f;
    const float* vr = vin + (size_t)wid * 64 + c4;
    ax = w * vr[0]; ay = w * vr[1]; az = w * vr[2]; aw = w * vr[3];
  }
  for (int e = e0; e < e1; e += 8) {
    int i0 = e + quad, i1 = e + 4 + quad;
    int a0 = (i0 < e1), a1 = (i1 < e1);
    int j0 = a0 ? i0 : e0;
    int j1 = a1 ? i1 : e0;
    int cc0 = colA[j0];
    int cc1 = colA[j1];
    float w0 = a0 ? wgt[j0] : 0.0f;
    float w1 = a1 ? wgt[j1] : 0.0f;
    const float* p0 = vin + (size_t)cc0 * 64 + c4;
    const float* p1 = vin + (size_t)cc1 * 64 + c4;
    float v00 = p0[0], v01 = p0[1], v02 = p0[2], v03 = p0[3];
    float v10 = p1[0], v11 = p1[1], v12 = p1[2], v13 = p1[3];
    ax += w0 * v00 + w1 * v10;
    ay += w0 * v01 + w1 * v11;
    az += w0 * v02 + w1 * v12;
    aw += w0 * v03 + w1 * v13;
  }
  // reduce across quads (lanes l15, l15+16, l15+32, l15+48)
  ax += __shfl_xor(ax, 16); ax += __shfl_xor(ax, 32);
  ay += __shfl_xor(ay, 16); ay += __shfl_xor(ay, 32);
  az += __shfl_xor(az, 16); az += __shfl_xor(az, 32);
  aw += __shfl_xor(aw, 16); aw += __shfl_xor(aw, 32);
  if (quad == 0) {
    int b = idx_at(batch, wid, *flag);
    float* o = vout + (size_t)wid * 64 + c4;
    float4 r;
    r.x = (1.0f - ALPHA) * ax + ((b == c4 + 0) ? ALPHA : 0.0f);
    r.y = (1.0f - ALPHA) * ay + ((b == c4 + 1) ? ALPHA : 0.0f);
    r.z = (1.0f - ALPHA) * az + ((b == c4 + 2) ? ALPHA : 0.0f);
    r.w = (1.0f - ALPHA) * aw + ((b == c4 + 3) ? ALPHA : 0.0f);
    *(float4*)o = r;
  }
}

// pooled_unnorm partials: 48 f-tiles x 16 node-chunks, lane = graph id
__global__ void spmm_kernel(const float* __restrict__ S, const float* __restrict__ x,
                            float* __restrict__ partial) {
  int wid = (blockIdx.x * blockDim.x + threadIdx.x) >> 6;   // 768 waves
  int lane = threadIdx.x & 63;
  int ft = wid % 48, ch = wid / 48;
  if (ch >= 16) return;
  int f0 = ft * 16;
  int n0 = ch * 1250, n1 = n0 + 1250;
  float acc[16];
#pragma unroll
  for (int f = 0; f < 16; ++f) acc[f] = 0.0f;
  for (int n = n0; n < n1; ++n) {
    float sv = S[n * 64 + lane];
    const float* xr = x + (size_t)n * DF + f0;
#pragma unroll
    for (int f = 0; f < 16; ++f) acc[f] += sv * xr[f];
  }
  float* pr = partial + ((size_t)(ch * 64 + lane)) * DF + f0;
#pragma unroll
  for (int f = 0; f < 16; ++f) pr[f] = acc[f];
}

__global__ void reduce_pool_kernel(const float* __restrict__ partial, const int* __restrict__ cntb,
                                   float* __restrict__ pooled) {
  int i = blockIdx.x * blockDim.x + threadIdx.x;
  if (i >= 64 * DF) return;
  int b = i / DF, f = i - b * DF;
  float s = 0.0f;
  for (int c = 0; c < 16; ++c) s += partial[((size_t)(c * 64 + b)) * DF + f];
  int cnt = cntb[b]; if (cnt < 1) cnt = 1;
  pooled[i] = s / (float)cnt;
}

// C[M,N] = act(A[M,K] @ W[N,K]^T + bias), optionally accumulate into C
__global__ void mlp_layer_kernel(const float* __restrict__ A, const float* __restrict__ W,
                                 const float* __restrict__ bias, float* __restrict__ C,
                                 int M, int N, int K, int relu, int accum) {
  int i = blockIdx.x * blockDim.x + threadIdx.x;
  if (i >= M * N) return;
  int mrow = i / N, n = i - mrow * N;
  float acc = bias[n];
  const float4* a4 = (const float4*)(A + (size_t)mrow * K);
  const float4* w4 = (const float4*)(W + (size_t)n * K);
  int k4 = K >> 2;
#pragma unroll 4
  for (int k = 0; k < k4; ++k) {
    float4 av = a4[k], wv = w4[k];
    acc += av.x * wv.x + av.y * wv.y + av.z * wv.z + av.w * wv.w;
  }
  if (relu) acc = fmaxf(acc, 0.0f);
  if (accum) C[i] += acc; else C[i] = acc;
}

// ---------------- GRU recurrent kernel (R3-proven: 1 wave/block, flag
// exchange, weights in VGPRs/AGPRs). 512 blocks x 64 threads. ----------------
__global__ __launch_bounds__(64, 1) void gru_kernel(
    const float* __restrict__ seq,
    const float* __restrict__ wih_f, const float* __restrict__ whh_f,
    const float* __restrict__ bih_f, const float* __restrict__ bhh_f,
    const float* __restrict__ wih_b, const float* __restrict__ whh_b,
    const float* __restrict__ bih_b, const float* __restrict__ bhh_b,
    unsigned* __restrict__ hbuf, unsigned* __restrict__ hflag,
    float* __restrict__ y_seq) {
  __shared__ unsigned short hl[8 * 648];   // [8 seqs][h(512) | x(128) | pad]

  const int lane = threadIdx.x;           // 0..63
  const int quad = lane >> 4, l15 = lane & 15;
  const int d  = blockIdx.x >> 8;         // 0 fwd, 1 bwd
  const int g  = (blockIdx.x >> 5) & 7;   // 8 groups
  const int rk = blockIdx.x & 31;         // 32 ranks
  const int seqbase = g * 8;
  const int c0 = rk * 16;

  const float* WHHd = d ? whh_b : whh_f;
  const float* WIHd = d ? wih_b : wih_f;
  const float* BIHd = d ? bih_b : bih_f;
  const float* BHHd = d ? bhh_b : bhh_f;

  // ---- weight fragments -> registers (once) ----
  auto ldw = [&](int gcol, int j) -> short8 {
    int k0 = j * 32 + quad * 8;
    const float* p = (k0 < 512) ? (WHHd + (size_t)gcol * 512 + k0)
                                : (WIHd + (size_t)gcol * 128 + (k0 - 512));
    float4 f0 = *(const float4*)p;
    float4 f1 = *(const float4*)(p + 4);
    short8 r;
    r[0] = (short)f2b(f0.x); r[1] = (short)f2b(f0.y);
    r[2] = (short)f2b(f0.z); r[3] = (short)f2b(f0.w);
    r[4] = (short)f2b(f1.x); r[5] = (short)f2b(f1.y);
    r[6] = (short)f2b(f1.z); r[7] = (short)f2b(f1.w);
    return r;
  };
  short8 wr[20], wz[20], wn[20];
#pragma unroll
  for (int j = 0; j < 20; ++j) {
    wr[j] = ldw(c0 + l15, j);
    wz[j] = ldw(512 + c0 + l15, j);
    wn[j] = ldw(1024 + c0 + l15, j);
  }

  // ---- x staging: 1 lane does (seq = lane>>3, 16 k-chunk) ----
  auto stage_x = [&](int t_x) {
    int tt = d ? (127 - t_x) : t_x;
    int s = lane >> 3, k0 = (lane & 7) * 16;
    const float* sp = seq + (size_t)(seqbase + s) * (TSEQ * SF) + tt * SF + k0;
    float4 a = *(const float4*)sp;
    float4 b = *(const float4*)(sp + 4);
    float4 c = *(const float4*)(sp + 8);
    float4 e = *(const float4*)(sp + 12);
    unsigned* xq = (unsigned*)(hl + s * 648 + 512 + k0);   // 16B aligned
    xq[0] = (unsigned)f2b(a.x) | ((unsigned)f2b(a.y) << 16);
    xq[1] = (unsigned)f2b(a.z) | ((unsigned)f2b(a.w) << 16);
    xq[2] = (unsigned)f2b(b.x) | ((unsigned)f2b(b.y) << 16);
    xq[3] = (unsigned)f2b(b.z) | ((unsigned)f2b(b.w) << 16);
    xq[4] = (unsigned)f2b(c.x) | ((unsigned)f2b(c.y) << 16);
    xq[5] = (unsigned)f2b(c.z) | ((unsigned)f2b(c.w) << 16);
    xq[6] = (unsigned)f2b(e.x) | ((unsigned)f2b(e.y) << 16);
    xq[7] = (unsigned)f2b(e.z) | ((unsigned)f2b(e.w) << 16);
  };

  // ---- init: h(0)=0, stage x(0) ----
  for (int i = lane; i < 8 * 512; i += 64)
    hl[(i >> 9) * 648 + (i & 511)] = 0;
  stage_x(0);

  const float b_r  = BIHd[c0 + l15] + BHHd[c0 + l15];
  const float b_z  = BIHd[512 + c0 + l15] + BHHd[512 + c0 + l15];
  const float b_in = BIHd[1024 + c0 + l15];
  const float b_hn = BHHd[1024 + c0 + l15];

  float hprev[4] = {0, 0, 0, 0};
  float msum[4]  = {0, 0, 0, 0};
  float mxv[4]   = {-1e30f, -1e30f, -1e30f, -1e30f};

  for (int t = 0; t < 128; ++t) {
    // ---- GEMM: 60 MFMAs, A-frag read once per kc, shared by r/z/n ----
    f32x4 ar = {0, 0, 0, 0}, az = {0, 0, 0, 0};
    f32x4 anh = {0, 0, 0, 0}, anx = {0, 0, 0, 0};
    const unsigned short* arow = hl + (l15 & 7) * 648 + quad * 8;
#pragma unroll
    for (int kc = 0; kc < 20; ++kc) {
      short8 af = *(const short8*)(arow + kc * 32);
      ar = __builtin_amdgcn_mfma_f32_16x16x32_bf16(af, wr[kc], ar, 0, 0, 0);
      az = __builtin_amdgcn_mfma_f32_16x16x32_bf16(af, wz[kc], az, 0, 0, 0);
      if (kc < 16)
        anh = __builtin_amdgcn_mfma_f32_16x16x32_bf16(af, wn[kc], anh, 0, 0, 0);
      else
        anx = __builtin_amdgcn_mfma_f32_16x16x32_bf16(af, wn[kc], anx, 0, 0, 0);
    }

    // ---- gates: fully in-register (lane: col=l15, rows=quad*4+rr) ----
    float h2v[4];
#pragma unroll
    for (int rr = 0; rr < 4; ++rr) {
      float r = 1.0f / (1.0f + __expf(-(ar[rr] + b_r)));
      float z = 1.0f / (1.0f + __expf(-(az[rr] + b_z)));
      float narg = anx[rr] + b_in + r * (anh[rr] + b_hn);
      float e2 = __expf(-2.0f * fabsf(narg));
      float nt = (1.0f - e2) / (1.0f + e2);
      nt = (narg < 0.0f) ? -nt : nt;
      float h2 = (1.0f - z) * nt + z * hprev[rr];
      hprev[rr] = h2; msum[rr] += h2; mxv[rr] = fmaxf(mxv[rr], h2);
      h2v[rr] = h2;
    }

    if (t < 127) {
      const int slot = (t + 1) & 1;
      const unsigned tag = (unsigned)(t + 1);
      // ---- store packed h (rows 0-7 live in lanes 0-31) ----
#pragma unroll
      for (int rr = 0; rr < 4; ++rr) {
        unsigned me = f2b(h2v[rr]);
        unsigned nb = (unsigned)__shfl_xor((int)me, 1);
        if (lane < 32 && !(lane & 1)) {
          int row = (lane >> 4) * 4 + rr;
          unsigned word = (me & 0xFFFFu) | (nb << 16);
          unsigned* dp = hbuf +
              ((size_t)((slot * 2 + d) * 64 + seqbase + row)) * 256 +
              (unsigned)((c0 + (lane & 15)) >> 1);
          asm volatile("global_store_dword %0, %1, off sc0 sc1"
                       :: "v"(dp), "v"(word) : "memory");
        }
      }
      asm volatile("s_waitcnt vmcnt(0)" ::: "memory");   // release: data ack'd
      if (lane == 0) {
        unsigned* fpo = hflag + ((size_t)(slot * 2 + d) * 8 + g) * 64 + rk;
        unsigned tv = tag;
        asm volatile("global_store_dword %0, %1, off sc0 sc1"
                     :: "v"(fpo), "v"(tv) : "memory");
      }
      // ---- stage x(t+1) (independent; overlaps flag propagation) ----
      stage_x(t + 1);
      // ---- poll 32 rank flags ----
      const unsigned* fp = hflag + ((size_t)(slot * 2 + d) * 8 + g) * 64 + (lane & 31);
      int guard = 0;
      unsigned fv;
      for (;;) {
        asm volatile("global_load_dword %0, %1, off sc0 sc1"
                     : "=v"(fv) : "v"(fp) : "memory");
        asm volatile("s_waitcnt vmcnt(0)" ::: "memory");
        __builtin_amdgcn_sched_barrier(0);
        if (__all(fv == tag)) break;
        if (++guard > (1 << 20)) break;
        __builtin_amdgcn_s_sleep(1);
      }
      // ---- bulk gather: 8 KB slab (chunk c = seq c), scatter to LDS ----
      const unsigned* db = hbuf + (size_t)((slot * 2 + d) * 64 + seqbase) * 256;
      u32x4 w[8];
#pragma unroll
      for (int c = 0; c < 8; ++c)
        asm volatile("global_load_dwordx4 %0, %1, off sc0 sc1"
                     : "=v"(w[c]) : "v"(db + c * 256 + lane * 4) : "memory");
      asm volatile("s_waitcnt vmcnt(0)" ::: "memory");
      __builtin_amdgcn_sched_barrier(0);
#pragma unroll
      for (int c = 0; c < 8; ++c) {
        unsigned* dp = (unsigned*)(hl + c * 648) + lane * 4;   // 16B aligned
        dp[0] = w[c][0]; dp[1] = w[c][1]; dp[2] = w[c][2]; dp[3] = w[c][3];
      }
    }
  }

  // ---- epilogue: seq1 + seq2 = mean + max over T ----
  if (lane < 32) {
#pragma unroll
    for (int rr = 0; rr < 4; ++rr) {
      int row = (lane >> 4) * 4 + rr;
      y_seq[(size_t)(seqbase + row) * 1024 + d * 512 + c0 + l15] =
          msum[rr] * (1.0f / 128.0f) + mxv[rr];
    }
  }
}

// ---------------- launcher ----------------
extern "C" void kernel_launch(void* const* d_in, const int* in_sizes, int n_in,
                              void* d_out, int out_size, void* d_ws, size_t ws_size,
                              hipStream_t stream) {
  const float* x      = (const float*)d_in[0];
  const int*   eidx   = (const int*)d_in[1];
  const float* seq    = (const float*)d_in[2];
  const int*   batch  = (const int*)d_in[3];
  const float* wih_f  = (const float*)d_in[4];
  const float* whh_f  = (const float*)d_in[5];
  const float* bih_f  = (const float*)d_in[6];
  const float* bhh_f  = (const float*)d_in[7];
  const float* wih_b  = (const float*)d_in[8];
  const float* whh_b  = (const float*)d_in[9];
  const float* bih_b  = (const float*)d_in[10];
  const float* bhh_b  = (const float*)d_in[11];
  const float* mg_w0  = (const float*)d_in[12];
  const float* mg_b0  = (const float*)d_in[13];
  const float* mg_w1  = (const float*)d_in[14];
  const float* mg_b1  = (const float*)d_in[15];
  const float* mg_w2  = (const float*)d_in[16];
  const float* mg_b2  = (const float*)d_in[17];
  const float* ms_w0  = (const float*)d_in[18];
  const float* ms_b0  = (const float*)d_in[19];
  const float* ms_w1  = (const float*)d_in[20];
  const float* ms_b1  = (const float*)d_in[21];
  const float* ms_w2  = (const float*)d_in[22];
  const float* ms_b2  = (const float*)d_in[23];
  float* out = (float*)d_out;
  char* ws = (char*)d_ws;

  int*   deg     = (int*)(ws + OFF_DEG);
  int*   csrc    = (int*)(ws + OFF_CSRC);
  int*   cntb    = (int*)(ws + OFF_CNTB);
  int*   flag    = (int*)(ws + OFF_FLAG64);
  int*   row_ptr = (int*)(ws + OFF_ROWPTR);
  int*   cursor  = (int*)(ws + OFF_CURSOR);
  float* dinv    = (float*)(ws + OFF_DINV);
  int*   colA    = (int*)(ws + OFF_COL);
  float* wgtA    = (float*)(ws + OFF_WGT);
  float* V0      = (float*)(ws + OFF_V0);
  float* V1      = (float*)(ws + OFF_V1);
  unsigned* hbuf = (unsigned*)(ws + OFF_HBUF);
  unsigned* hflag= (unsigned*)(ws + OFF_HFLAG);
  float* y_seq   = (float*)(ws + OFF_YSEQ);
  float* sh1     = (float*)(ws + OFF_SH1);
  float* sh2     = (float*)(ws + OFF_SH2);
  float* part    = (float*)(ws + OFF_PART);
  float* pooled  = (float*)(ws + OFF_POOL);
  float* gh1     = (float*)(ws + OFF_GH1);
  float* gh2     = (float*)(ws + OFF_GH2);

  // ---- graph prep (CSR for A^T, degrees, batch counts) ----
  zero_ints_kernel<<<(ZERO_INTS + 255) / 256, 256, 0, stream>>>((int*)ws, (int)ZERO_INTS);
  zero_ints_kernel<<<8, 256, 0, stream>>>((int*)(ws + OFF_HFLAG), 2048);  // rank flags
  detect_i64_kernel<<<1, 64, 0, stream>>>(eidx, flag);
  hist_kernel<<<(NE + 255) / 256, 256, 0, stream>>>(eidx, batch, deg, csrc, cntb, flag);
  dinv_kernel<<<(NN + 255) / 256, 256, 0, stream>>>(deg, dinv);
  scan_kernel<<<1, 1024, 0, stream>>>(csrc, row_ptr, cursor);
  fill_kernel<<<(NE + 255) / 256, 256, 0, stream>>>(eidx, dinv, cursor, colA, wgtA, flag);
  v0init_kernel<<<(NN * 64 + 255) / 256, 256, 0, stream>>>(batch, V0, flag);

  // ---- APPNP: 16 hop dispatches (max TLP: 20000 waves each) ----
  for (int h = 0; h < 16; ++h) {
    const float* vin = (h & 1) ? V1 : V0;
    float* vout = (h & 1) ? V0 : V1;
    hop_kernel<<<(NN * 64 + 255) / 256, 256, 0, stream>>>(vin, vout, row_ptr, colA,
                                                          wgtA, dinv, batch, flag);
  }

  // ---- BiGRU (fused gi + recurrent + pooling), 1 wave/block ----
  gru_kernel<<<512, 64, 0, stream>>>(
      seq, wih_f, whh_f, bih_f, bhh_f, wih_b, whh_b, bih_b, bhh_b, hbuf, hflag, y_seq);

  // ---- seq MLP: 1024 -> 512 -> 256 -> 14 (writes d_out) ----
  mlp_layer_kernel<<<(64 * 512 + 255) / 256, 256, 0, stream>>>(y_seq, ms_w0, ms_b0, sh1,
                                                               64, 512, 1024, 1, 0);
  mlp_layer_kernel<<<(64 * 256 + 255) / 256, 256, 0, stream>>>(sh1, ms_w1, ms_b1, sh2,
                                                               64, 256, 512, 1, 0);
  mlp_layer_kernel<<<(64 * NCLS + 255) / 256, 256, 0, stream>>>(sh2, ms_w2, ms_b2, out,
                                                                64, NCLS, 256, 0, 0);

  // ---- pooled = (S^T x) / cnt ; after 16 hops result is in V0 ----
  spmm_kernel<<<(768 * 64) / 256, 256, 0, stream>>>(V0, x, part);
  reduce_pool_kernel<<<(64 * DF + 255) / 256, 256, 0, stream>>>(part, cntb, pooled);

  // ---- graph MLP: 768 -> 384 -> 192 -> 14 (accumulates into d_out) ----
  mlp_layer_kernel<<<(64 * 384 + 255) / 256, 256, 0, stream>>>(pooled, mg_w0, mg_b0, gh1,
                                                               64, 384, 768, 1, 0);
  mlp_layer_kernel<<<(64 * 192 + 255) / 256, 256, 0, stream>>>(gh1, mg_w1, mg_b1, gh2,
                                                               64, 192, 384, 1, 0);
  mlp_layer_kernel<<<(64 * NCLS + 255) / 256, 256, 0, stream>>>(gh2, mg_w2, mg_b2, out,
                                                                64, NCLS, 192, 0, 1);
  (void)in_sizes; (void)n_in; (void)out_size; (void)ws_size;
}